// Round 5
// baseline (1727.974 us; speedup 1.0000x reference)
//
#include <hip/hip_runtime.h>

// SSFM on MI355X. N = 262144 = 512*512, B = 4 batches.
// Persistent cooperative kernel, round-5: XCD-locality-aware cache routing.
// Each 64B line of the ping-pong buffers has one producer unit and one
// consumer unit; if both on the same XCD -> plain store + sc0 load (local L2),
// else sc1 store/load (LLC). Real XCD ids via s_getreg(HW_REG_XCC_ID) table,
// so correctness does not depend on the block->XCD mapping.

static constexpr double PI_D = 3.14159265358979323846;

__device__ __forceinline__ float2 cadd(float2 a, float2 b){ return make_float2(a.x+b.x, a.y+b.y); }
__device__ __forceinline__ float2 csub(float2 a, float2 b){ return make_float2(a.x-b.x, a.y-b.y); }
__device__ __forceinline__ float2 cmul(float2 a, float2 b){
  return make_float2(fmaf(a.x, b.x, -(a.y*b.y)), fmaf(a.x, b.y, a.y*b.x));
}
__device__ __forceinline__ float2 cmulc(float2 a, float2 b){ // a * conj(b)
  return make_float2(fmaf(a.x, b.x, a.y*b.y), fmaf(a.y, b.x, -(a.x*b.y)));
}

// Bank-decorrelating bijection on [0,512).
__device__ __forceinline__ int sg(int e){
  int d2 = (e>>6)&7, d1 = (e>>3)&7;
  return e ^ (d2<<3) ^ d1 ^ d2;
}

// ---- scoped global I/O (inline asm, manual waits) ----
__device__ __forceinline__ float2 u2f(unsigned long long u){ union{unsigned long long u; float2 f;}c; c.u=u; return c.f; }
__device__ __forceinline__ unsigned long long f2u(float2 f){ union{unsigned long long u; float2 f;}c; c.f=f; return c.u; }

__device__ __forceinline__ void gl_near(unsigned long long &d, unsigned long long bp, unsigned voff){
  asm volatile("global_load_dwordx2 %0, %1, %2 sc0" : "=&v"(d) : "v"(voff), "s"(bp) : "memory");
}
__device__ __forceinline__ void gl_far(unsigned long long &d, unsigned long long bp, unsigned voff){
  asm volatile("global_load_dwordx2 %0, %1, %2 sc0 sc1" : "=&v"(d) : "v"(voff), "s"(bp) : "memory");
}
__device__ __forceinline__ void gs_near(unsigned long long bp, unsigned voff, unsigned long long v){
  asm volatile("global_store_dwordx2 %0, %1, %2" :: "v"(voff), "v"(v), "s"(bp) : "memory");
}
__device__ __forceinline__ void gs_far(unsigned long long bp, unsigned voff, unsigned long long v){
  asm volatile("global_store_dwordx2 %0, %1, %2 sc0 sc1" :: "v"(voff), "v"(v), "s"(bp) : "memory");
}
__device__ __forceinline__ void vwait(){
  asm volatile("s_waitcnt vmcnt(0)" ::: "memory");
  __builtin_amdgcn_sched_barrier(0);
}

template<int INV>
__device__ __forceinline__ void dft8(float2 r[8]){
  const float RS = 0.7071067811865476f;
  float2 t0=cadd(r[0],r[4]), t4=csub(r[0],r[4]);
  float2 t1=cadd(r[1],r[5]), t5=csub(r[1],r[5]);
  float2 t2=cadd(r[2],r[6]), t6=csub(r[2],r[6]);
  float2 t3=cadd(r[3],r[7]), t7=csub(r[3],r[7]);
  float2 u1,u2,u3;
  if(!INV){
    u1 = make_float2((t5.x+t5.y)*RS, (t5.y-t5.x)*RS);
    u2 = make_float2(t6.y, -t6.x);
    u3 = make_float2((t7.y-t7.x)*RS, -(t7.x+t7.y)*RS);
  } else {
    u1 = make_float2((t5.x-t5.y)*RS, (t5.x+t5.y)*RS);
    u2 = make_float2(-t6.y, t6.x);
    u3 = make_float2(-(t7.x+t7.y)*RS, (t7.x-t7.y)*RS);
  }
  float2 e0=cadd(t0,t2), e1=csub(t0,t2), e2=cadd(t1,t3), e3=csub(t1,t3);
  float2 f3 = (!INV)? make_float2(e3.y,-e3.x) : make_float2(-e3.y,e3.x);
  r[0]=cadd(e0,e2); r[4]=csub(e0,e2); r[2]=cadd(e1,f3); r[6]=csub(e1,f3);
  float2 o0=cadd(t4,u2), o1=csub(t4,u2), o2=cadd(u1,u3), o3=csub(u1,u3);
  float2 g3 = (!INV)? make_float2(o3.y,-o3.x) : make_float2(-o3.y,o3.x);
  r[1]=cadd(o0,o2); r[5]=csub(o0,o2); r[3]=cadd(o1,g3); r[7]=csub(o1,g3);
}

// ---------- register-twiddle 512-pt FFTs (persistent kernel) ----------
__device__ __forceinline__ void fwd512(float2 r[8], int l, int p, int j,
                                       const float2* t1, const float2* t2, float2* ex){
  dft8<0>(r);
  #pragma unroll
  for(int q=1;q<8;q++) r[q]=cmul(r[q],t1[q-1]);
  #pragma unroll
  for(int q=0;q<8;q++) ex[sg(l+64*q)] = r[q];
  #pragma unroll
  for(int m=0;m<8;m++) r[m] = ex[sg(64*j+p+8*m)];
  dft8<0>(r);
  #pragma unroll
  for(int q=1;q<8;q++) r[q]=cmul(r[q],t2[q-1]);
  #pragma unroll
  for(int q=0;q<8;q++) ex[sg(64*j+p+8*q)] = r[q];
  #pragma unroll
  for(int m=0;m<8;m++) r[m] = ex[sg(64*j+8*p+m)];
  dft8<0>(r);
}
__device__ __forceinline__ void inv512(float2 r[8], int l, int p, int j,
                                       const float2* t1, const float2* t2, float2* ex){
  dft8<1>(r);
  #pragma unroll
  for(int m=0;m<8;m++) ex[sg(64*j+8*p+m)] = r[m];
  #pragma unroll
  for(int q=0;q<8;q++) r[q] = ex[sg(64*j+p+8*q)];
  #pragma unroll
  for(int q=1;q<8;q++) r[q]=cmulc(r[q],t2[q-1]);
  dft8<1>(r);
  #pragma unroll
  for(int m=0;m<8;m++) ex[sg(64*j+p+8*m)] = r[m];
  #pragma unroll
  for(int q=0;q<8;q++) r[q] = ex[sg(l+64*q)];
  #pragma unroll
  for(int q=1;q<8;q++) r[q]=cmulc(r[q],t1[q-1]);
  dft8<1>(r);
}

// ---------- original sincos-based fft512 (fallback kernels) ----------
template<int INV>
__device__ __forceinline__ void fft512(float2 r[8], int l, float2* ex){
  const float W512 = (float)(2.0*PI_D/512.0);
  const float W64  = (float)(2.0*PI_D/64.0);
  int j = l>>3, p = l&7;
  float s,c;
  if(!INV){
    dft8<0>(r);
    __sincosf(-W512*(float)l, &s, &c);
    float2 w = make_float2(c,s), cur = w;
    #pragma unroll
    for(int q=1;q<8;q++){ r[q]=cmul(r[q],cur); cur=cmul(cur,w); }
    #pragma unroll
    for(int q=0;q<8;q++) ex[sg(l + 64*q)] = r[q];
    #pragma unroll
    for(int m=0;m<8;m++) r[m] = ex[sg(64*j + p + 8*m)];
    dft8<0>(r);
    __sincosf(-W64*(float)p, &s, &c);
    w = make_float2(c,s); cur = w;
    #pragma unroll
    for(int q=1;q<8;q++){ r[q]=cmul(r[q],cur); cur=cmul(cur,w); }
    #pragma unroll
    for(int q=0;q<8;q++) ex[sg(64*j + p + 8*q)] = r[q];
    #pragma unroll
    for(int m=0;m<8;m++) r[m] = ex[sg(64*j + 8*p + m)];
    dft8<0>(r);
  } else {
    dft8<1>(r);
    #pragma unroll
    for(int m=0;m<8;m++) ex[sg(64*j + 8*p + m)] = r[m];
    #pragma unroll
    for(int q=0;q<8;q++) r[q] = ex[sg(64*j + p + 8*q)];
    __sincosf(W64*(float)p, &s, &c);
    float2 w = make_float2(c,s), cur = w;
    #pragma unroll
    for(int q=1;q<8;q++){ r[q]=cmul(r[q],cur); cur=cmul(cur,w); }
    dft8<1>(r);
    #pragma unroll
    for(int m=0;m<8;m++) ex[sg(64*j + p + 8*m)] = r[m];
    #pragma unroll
    for(int q=0;q<8;q++) r[q] = ex[sg(l + 64*q)];
    __sincosf(W512*(float)l, &s, &c);
    w = make_float2(c,s); cur = w;
    #pragma unroll
    for(int q=1;q<8;q++){ r[q]=cmul(r[q],cur); cur=cmul(cur,w); }
    dft8<1>(r);
  }
}

// Permuted dispersion tables + barrier-slot zeroing.
__global__ __launch_bounds__(512) void kSetup(float2* __restrict__ dispF, float2* __restrict__ dispH,
                                              int* __restrict__ bar){
  int m  = blockIdx.x*512 + threadIdx.x;
  if (m < 16384) bar[m] = 0;
  int k1 = m >> 9, k2 = m & 511;
  int k  = k1 + (k2 << 9);
  int ks = (k < 131072) ? k : k - 262144;
  float fv  = (float)ks / 262144.0f;
  float tpf = 6.28318548202514648f * fv;
  float e2  = tpf * tpf;
  const float bh = 10.8350000381469727f;
  float phF = (bh * 1.25f)  * e2;
  float phH = (bh * 0.625f) * e2;
  double sF,cF,sH,cH;
  sincos((double)phF, &sF, &cF);
  sincos((double)phH, &sH, &cH);
  const float aco = -0.023000000044703484f;
  double scF = exp((double)(aco*1.25f))  / 262144.0;
  double scH = exp((double)(aco*0.625f)) / 262144.0;
  dispF[m] = make_float2((float)(cF*scF), (float)(sF*scF));
  dispH[m] = make_float2((float)(cH*scH), (float)(sH*scH));
}

// ---------------- fallback multi-kernel path (proven) ----------------
__global__ __launch_bounds__(512) void kA(const float2* __restrict__ src, float2* __restrict__ dst,
                                          const float2* __restrict__ disp){
  __shared__ float2 ex[8][512];
  int t = threadIdx.x, w = t>>6, l = t&63;
  int k1 = blockIdx.x*8 + w;
  size_t base = ((size_t)blockIdx.y<<18) + (size_t)k1*512;
  const float2* s = src + base;
  float2* d = dst + base;
  float2 r[8];
  #pragma unroll
  for(int m=0;m<8;m++) r[m] = s[l + 64*m];
  fft512<0>(r, l, ex[w]);
  int p=l&7, j=l>>3;
  const float2* dp = disp + (size_t)k1*512;
  #pragma unroll
  for(int q=0;q<8;q++) r[q] = cmul(r[q], dp[64*q + 8*p + j]);
  fft512<1>(r, l, ex[w]);
  float c1 = (float)(2.0*PI_D/262144.0)*(float)k1;
  float sb,cb,ss,cs;
  __sincosf(c1*(float)l, &sb, &cb);
  __sincosf(c1*64.0f,    &ss, &cs);
  float2 tw = make_float2(cb,sb), st = make_float2(cs,ss);
  #pragma unroll
  for(int m=0;m<8;m++){ d[l+64*m] = cmul(r[m], tw); tw = cmul(tw, st); }
}

template<int MODE>
__global__ __launch_bounds__(512) void kB(const float* __restrict__ xr, const float* __restrict__ xi,
                                          const float2* __restrict__ src, float2* __restrict__ dst,
                                          float* __restrict__ outp){
  __shared__ float2 tile[8][514];
  int t=threadIdx.x, w=t>>6, l=t&63;
  int c0 = blockIdx.x*8;
  size_t base = ((size_t)blockIdx.y<<18);
  #pragma unroll
  for(int i=0;i<8;i++){
    int rr = i*64 + (t>>3), cc = t&7;
    size_t a = base + (size_t)rr*512 + (size_t)(c0 + cc);
    if(MODE==0) tile[cc][sg(rr)] = make_float2(xr[a], xi[a]);
    else        tile[cc][sg(rr)] = src[a];
  }
  __syncthreads();
  float2 r[8];
  int p=l&7, j=l>>3;
  int n2 = c0 + w;
  if(MODE==0){
    #pragma unroll
    for(int m=0;m<8;m++) r[m] = tile[w][sg(l + 64*m)];
  } else {
    #pragma unroll
    for(int q=0;q<8;q++) r[q] = tile[w][sg(64*q + 8*p + j)];
    fft512<1>(r, l, tile[w]);
  }
  if(MODE==1){
    #pragma unroll
    for(int m=0;m<8;m++){
      int n1 = l + 64*m;
      float wv = 1.0f;
      if(n1==0 && n2<100){
        float ang = (6.28318548202514648f*(float)n2)*0.005f;
        wv = 0.54f - 0.46f*cosf(ang);
      } else if(n1==511 && n2>=412){
        float ang = (6.28318548202514648f*(float)(n2-312))*0.005f;
        wv = 0.54f - 0.46f*cosf(ang);
      }
      float2 qv = make_float2(r[m].x*wv, r[m].y*wv);
      float aq2 = fmaf(qv.x,qv.x, qv.y*qv.y);
      float phi = (aq2 * 1.26999998092651367f) * (-1.25f);
      float sp,cp; __sincosf(phi,&sp,&cp);
      r[m] = cmul(qv, make_float2(cp,sp));
    }
  }
  if(MODE==2){
    #pragma unroll
    for(int m=0;m<8;m++) tile[w][sg(l + 64*m)] = r[m];
    __syncthreads();
    #pragma unroll
    for(int i=0;i<8;i++){
      int rr = i*64 + (t>>3), cc = t&7;
      float2 v = tile[cc][sg(rr)];
      size_t a = base + (size_t)rr*512 + (size_t)(c0 + cc);
      outp[a] = v.x;
      outp[(size_t)(1<<20) + a] = v.y;
    }
    return;
  }
  fft512<0>(r, l, tile[w]);
  float c1 = -(float)(2.0*PI_D/262144.0)*(float)n2;
  float sb,cb,ss,cs;
  __sincosf(c1*(float)(8*p + j), &sb, &cb);
  __sincosf(c1*64.0f,            &ss, &cs);
  float2 tw=make_float2(cb,sb), st=make_float2(cs,ss);
  #pragma unroll
  for(int q=0;q<8;q++){ r[q]=cmul(r[q],tw); tw=cmul(tw,st); }
  #pragma unroll
  for(int q=0;q<8;q++) tile[w][sg(64*q + 8*p + j)] = r[q];
  __syncthreads();
  #pragma unroll
  for(int i=0;i<8;i++){
    int rr = i*64 + (t>>3), cc = t&7;
    dst[base + (size_t)rr*512 + (size_t)(c0 + cc)] = tile[cc][sg(rr)];
  }
}

// ---------------- persistent cooperative kernel ----------------
// One-shot barrier per (batch, phase). Entry drains asm stores (vmcnt).
__device__ __forceinline__ void gsync(int* bar, int slotbase, int phase){
  asm volatile("s_waitcnt vmcnt(0)" ::: "memory");
  __syncthreads();
  if (threadIdx.x == 0){
    int* cnt = bar + slotbase + phase*16;
    __hip_atomic_fetch_add(cnt, 1, __ATOMIC_RELAXED, __HIP_MEMORY_SCOPE_AGENT);
    while (__hip_atomic_load(cnt, __ATOMIC_RELAXED, __HIP_MEMORY_SCOPE_AGENT) != 64)
      __builtin_amdgcn_s_sleep(1);
    asm volatile("" ::: "memory");
  }
  __syncthreads();
}
__device__ __forceinline__ void gsyncAll(int* bar){
  asm volatile("s_waitcnt vmcnt(0)" ::: "memory");
  __syncthreads();
  if (threadIdx.x == 0){
    int* cnt = bar + 9000;
    __hip_atomic_fetch_add(cnt, 1, __ATOMIC_RELAXED, __HIP_MEMORY_SCOPE_AGENT);
    while (__hip_atomic_load(cnt, __ATOMIC_RELAXED, __HIP_MEMORY_SCOPE_AGENT) != 256)
      __builtin_amdgcn_s_sleep(1);
    asm volatile("" ::: "memory");
  }
  __syncthreads();
}

__global__ __launch_bounds__(512, 1) void ssfm_all(
    const float* __restrict__ xr, const float* __restrict__ xi,
    float* __restrict__ outp,
    float2* __restrict__ buf1, float2* __restrict__ buf2,
    const float2* __restrict__ dispF, const float2* __restrict__ dispH,
    int* __restrict__ bar, int* __restrict__ xcdtab)
{
  __shared__ float2 tile[8][514];
  __shared__ int sxcd[64];
  const int t=threadIdx.x, w=t>>6, l=t&63, p=l&7, j=l>>3;
  const int bi=blockIdx.x;
  const int lb=((bi&7)<<5)|(bi>>3);       // XCD-contiguous work mapping
  const int b=lb>>6, g=lb&63;
  const size_t base=(size_t)b<<18;
  const int k1=g*8+w, c0=g*8, n2=c0+w;
  const int slotbase = b*140*16;
  float2* exch = tile[w];
  const unsigned long long b1p=(unsigned long long)buf1, b2p=(unsigned long long)buf2;

  // ---- XCD discovery: table of every unit's physical XCC id ----
  int myx;
  asm("s_getreg_b32 %0, hwreg(HW_REG_XCC_ID)" : "=s"(myx));
  if (t==0)
    __hip_atomic_store(&xcdtab[lb], myx, __ATOMIC_RELAXED, __HIP_MEMORY_SCOPE_AGENT);
  gsyncAll(bar);
  if (t<64)
    sxcd[t] = __hip_atomic_load(&xcdtab[b*64+t], __ATOMIC_RELAXED, __HIP_MEMORY_SCOPE_AGENT);
  __syncthreads();
  // wave-uniform locality mask: bit i = peer unit (8i+w) on my XCD
  int smask=0;
  #pragma unroll
  for(int i=0;i<8;i++) smask |= (sxcd[8*i+w]==myx) ? (1<<i) : 0;
  smask = __builtin_amdgcn_readfirstlane(smask);

  // one-time register cache
  float2 t1[7], t2[7], dpF[8], dpH[8];
  #pragma unroll
  for(int q=1;q<8;q++){
    double s,c;
    sincos(-2.0*PI_D*(double)(l*q)/512.0,&s,&c); t1[q-1]=make_float2((float)c,(float)s);
    sincos(-2.0*PI_D*(double)(p*q)/64.0,&s,&c);  t2[q-1]=make_float2((float)c,(float)s);
  }
  float2 baseA, stA, baseB, stB;
  {
    double s,c;
    sincos( 2.0*PI_D*(double)(k1*l)/262144.0,&s,&c);        baseA=make_float2((float)c,(float)s);
    sincos( 2.0*PI_D*(double)(k1*64)/262144.0,&s,&c);       stA  =make_float2((float)c,(float)s);
    sincos(-2.0*PI_D*(double)(n2*(8*p+j))/262144.0,&s,&c);  baseB=make_float2((float)c,(float)s);
    sincos(-2.0*PI_D*(double)(n2*64)/262144.0,&s,&c);       stB  =make_float2((float)c,(float)s);
  }
  #pragma unroll
  for(int q=0;q<8;q++){
    int di=k1*512+64*q+8*p+j;
    dpF[q]=dispF[di]; dpH[q]=dispH[di];
  }
  float wvH=1.0f, wvT=1.0f;
  if(l==0  && n2<100)  wvH=0.54f-0.46f*cosf((6.28318548202514648f*(float)n2)*0.005f);
  if(l==63 && n2>=412) wvT=0.54f-0.46f*cosf((6.28318548202514648f*(float)(n2-312))*0.005f);

  // staging thread coords (shared by A and B tile I/O)
  const int cc8 = t&7, q8 = t>>3;          // B: col-in-group / row-base; A: row / col-base
  const unsigned voffB0 = (unsigned)(((size_t)base + (size_t)q8*512 + (size_t)(c0+cc8))*8);
  const unsigned voffA0 = (unsigned)(((size_t)base + (size_t)(8*g+cc8)*512 + (size_t)q8)*8);

  // ---- B0: input -> forward col-FFT -> twiddle -> buf1 ----
  {
    #pragma unroll
    for(int i=0;i<8;i++){
      int rr=i*64+q8;
      size_t a=base+(size_t)rr*512+(size_t)(c0+cc8);
      tile[cc8][sg(rr)]=make_float2(xr[a], xi[a]);
    }
    __syncthreads();
    float2 r[8];
    #pragma unroll
    for(int m=0;m<8;m++) r[m]=exch[sg(l+64*m)];
    fwd512(r,l,p,j,t1,t2,exch);
    float2 tw=baseB;
    #pragma unroll
    for(int q=0;q<8;q++){ r[q]=cmul(r[q],tw); tw=cmul(tw,stB); }
    #pragma unroll
    for(int q=0;q<8;q++) exch[sg(64*q+8*p+j)]=r[q];
    __syncthreads();
    unsigned voff=voffB0;
    #pragma unroll
    for(int i=0;i<8;i++){
      unsigned long long v=f2u(tile[cc8][sg(i*64+q8)]);
      if(smask&(1<<i)) gs_near(b1p,voff,v); else gs_far(b1p,voff,v);
      voff += 262144u;
    }
  }
  gsync(bar, slotbase, 0);
  // ---- A(half-dz): buf1 -> buf2 (LDS-staged rows) ----
  {
    unsigned long long v[8]; unsigned voff=voffA0;
    #pragma unroll
    for(int i=0;i<8;i++){
      if(smask&(1<<i)) gl_near(v[i],b1p,voff); else gl_far(v[i],b1p,voff);
      voff += 512u;
    }
    vwait();
    #pragma unroll
    for(int i=0;i<8;i++) tile[cc8][sg(i*64+q8)] = u2f(v[i]);
    __syncthreads();
    float2 r[8];
    #pragma unroll
    for(int m=0;m<8;m++) r[m]=exch[sg(l+64*m)];
    fwd512(r,l,p,j,t1,t2,exch);
    #pragma unroll
    for(int q=0;q<8;q++) r[q]=cmul(r[q],dpH[q]);
    inv512(r,l,p,j,t1,t2,exch);
    float2 tw=baseA;
    #pragma unroll
    for(int m=0;m<8;m++){ exch[sg(l+64*m)]=cmul(r[m],tw); tw=cmul(tw,stA); }
    __syncthreads();
    voff=voffA0;
    #pragma unroll
    for(int i=0;i<8;i++){
      unsigned long long vv=f2u(tile[cc8][sg(i*64+q8)]);
      if(smask&(1<<i)) gs_near(b2p,voff,vv); else gs_far(b2p,voff,vv);
      voff += 512u;
    }
  }
  gsync(bar, slotbase, 1);

  #pragma unroll 1
  for(int it=0; it<64; ++it){
    // ---- B1: buf2 -> inv col-FFT -> window -> NL -> fwd col-FFT -> buf1 ----
    {
      unsigned long long v[8]; unsigned voff=voffB0;
      #pragma unroll
      for(int i=0;i<8;i++){
        if(smask&(1<<i)) gl_near(v[i],b2p,voff); else gl_far(v[i],b2p,voff);
        voff += 262144u;
      }
      vwait();
      #pragma unroll
      for(int i=0;i<8;i++) tile[cc8][sg(i*64+q8)] = u2f(v[i]);
      __syncthreads();
      float2 r[8];
      #pragma unroll
      for(int q=0;q<8;q++) r[q]=exch[sg(64*q+8*p+j)];
      inv512(r,l,p,j,t1,t2,exch);
      #pragma unroll
      for(int m=0;m<8;m++){
        float wv = (m==0)? wvH : ((m==7)? wvT : 1.0f);
        float2 qv=make_float2(r[m].x*wv, r[m].y*wv);
        float aq2=fmaf(qv.x,qv.x, qv.y*qv.y);
        float phi=(aq2*1.26999998092651367f)*(-1.25f);
        float sp,cp; __sincosf(phi,&sp,&cp);
        r[m]=cmul(qv,make_float2(cp,sp));
      }
      fwd512(r,l,p,j,t1,t2,exch);
      float2 tw=baseB;
      #pragma unroll
      for(int q=0;q<8;q++){ r[q]=cmul(r[q],tw); tw=cmul(tw,stB); }
      #pragma unroll
      for(int q=0;q<8;q++) exch[sg(64*q+8*p+j)]=r[q];
      __syncthreads();
      voff=voffB0;
      #pragma unroll
      for(int i=0;i<8;i++){
        unsigned long long vv=f2u(tile[cc8][sg(i*64+q8)]);
        if(smask&(1<<i)) gs_near(b1p,voff,vv); else gs_far(b1p,voff,vv);
        voff += 262144u;
      }
    }
    gsync(bar, slotbase, 2+2*it);
    // ---- A: buf1 -> buf2 (dz; last iteration dz/2) ----
    {
      unsigned long long v[8]; unsigned voff=voffA0;
      #pragma unroll
      for(int i=0;i<8;i++){
        if(smask&(1<<i)) gl_near(v[i],b1p,voff); else gl_far(v[i],b1p,voff);
        voff += 512u;
      }
      vwait();
      #pragma unroll
      for(int i=0;i<8;i++) tile[cc8][sg(i*64+q8)] = u2f(v[i]);
      __syncthreads();
      float2 r[8];
      #pragma unroll
      for(int m=0;m<8;m++) r[m]=exch[sg(l+64*m)];
      fwd512(r,l,p,j,t1,t2,exch);
      const bool lastH=(it==63);
      #pragma unroll
      for(int q=0;q<8;q++){ float2 dq = lastH? dpH[q] : dpF[q]; r[q]=cmul(r[q],dq); }
      inv512(r,l,p,j,t1,t2,exch);
      float2 tw=baseA;
      #pragma unroll
      for(int m=0;m<8;m++){ exch[sg(l+64*m)]=cmul(r[m],tw); tw=cmul(tw,stA); }
      __syncthreads();
      voff=voffA0;
      #pragma unroll
      for(int i=0;i<8;i++){
        unsigned long long vv=f2u(tile[cc8][sg(i*64+q8)]);
        if(smask&(1<<i)) gs_near(b2p,voff,vv); else gs_far(b2p,voff,vv);
        voff += 512u;
      }
    }
    gsync(bar, slotbase, 3+2*it);
  }

  // ---- B2: buf2 -> inv col-FFT -> output planes ----
  {
    unsigned long long v[8]; unsigned voff=voffB0;
    #pragma unroll
    for(int i=0;i<8;i++){
      if(smask&(1<<i)) gl_near(v[i],b2p,voff); else gl_far(v[i],b2p,voff);
      voff += 262144u;
    }
    vwait();
    #pragma unroll
    for(int i=0;i<8;i++) tile[cc8][sg(i*64+q8)] = u2f(v[i]);
    __syncthreads();
    float2 r[8];
    #pragma unroll
    for(int q=0;q<8;q++) r[q]=exch[sg(64*q+8*p+j)];
    inv512(r,l,p,j,t1,t2,exch);
    #pragma unroll
    for(int m=0;m<8;m++) exch[sg(l+64*m)]=r[m];
    __syncthreads();
    #pragma unroll
    for(int i=0;i<8;i++){
      int rr=i*64+q8;
      float2 vv=tile[cc8][sg(rr)];
      size_t a=base+(size_t)rr*512+(size_t)(c0+cc8);
      outp[a]=vv.x;
      outp[(size_t)(1<<20)+a]=vv.y;
    }
  }
}

extern "C" void kernel_launch(void* const* d_in, const int* in_sizes, int n_in,
                              void* d_out, int out_size, void* d_ws, size_t ws_size,
                              hipStream_t stream) {
  (void)in_sizes; (void)n_in; (void)out_size; (void)ws_size;
  const float* xr = (const float*)d_in[0];
  const float* xi = (const float*)d_in[1];
  float* out = (float*)d_out;
  char* ws = (char*)d_ws;
  float2* buf1  = (float2*)ws;                      // 8 MB
  float2* buf2  = (float2*)(ws + ((size_t)8<<20));  // 8 MB
  float2* dispF = (float2*)(ws + ((size_t)16<<20)); // 2 MB
  float2* dispH = (float2*)(ws + ((size_t)18<<20)); // 2 MB
  int*    bar   = (int*)   (ws + ((size_t)20<<20)); // 64 KB one-shot barrier slots
  int*    xcdt  = (int*)   (ws + ((size_t)21<<20)); // 1 KB XCD table

  kSetup<<<dim3(512), dim3(512), 0, stream>>>(dispF, dispH, bar);

  void* args[] = {(void*)&xr,(void*)&xi,(void*)&out,(void*)&buf1,(void*)&buf2,
                  (void*)&dispF,(void*)&dispH,(void*)&bar,(void*)&xcdt};
  hipError_t e = hipLaunchCooperativeKernel((void*)ssfm_all, dim3(256), dim3(512),
                                            args, 0, stream);
  if (e != hipSuccess){
    // fallback: proven multi-kernel chain
    dim3 blk(512), gdim(64,4);
    kB<0><<<gdim, blk, 0, stream>>>(xr, xi, nullptr, buf1, nullptr);
    kA<<<gdim, blk, 0, stream>>>(buf1, buf2, dispH);
    for(int i=0;i<63;i++){
      kB<1><<<gdim, blk, 0, stream>>>(nullptr, nullptr, buf2, buf1, nullptr);
      kA<<<gdim, blk, 0, stream>>>(buf1, buf2, dispF);
    }
    kB<1><<<gdim, blk, 0, stream>>>(nullptr, nullptr, buf2, buf1, nullptr);
    kA<<<gdim, blk, 0, stream>>>(buf1, buf2, dispH);
    kB<2><<<gdim, blk, 0, stream>>>(nullptr, nullptr, buf2, nullptr, out);
  }
}

// Round 6
// 1619.466 us; speedup vs baseline: 1.0670x; 1.0670x over previous
//
#include <hip/hip_runtime.h>

// SSFM on MI355X. N = 262144 = 512*512, B = 4 batches.
// Persistent cooperative kernel, round-6:
//  (a) tile-blocked ping-pong layout: 8x8-complex tiles (512B) = one wave-load;
//      full-line granularity kills the 2x over-fetch + store-RFO of round 5.
//  (b) discovered work assignment: blocks claim slots by physical XCC_ID rank,
//      so batch = one XCD pair by construction -> near fraction 50% real.
// Near tiles: plain store + sc0 load (XCD L2). Far tiles: sc1 (LLC).

static constexpr double PI_D = 3.14159265358979323846;

__device__ __forceinline__ float2 cadd(float2 a, float2 b){ return make_float2(a.x+b.x, a.y+b.y); }
__device__ __forceinline__ float2 csub(float2 a, float2 b){ return make_float2(a.x-b.x, a.y-b.y); }
__device__ __forceinline__ float2 cmul(float2 a, float2 b){
  return make_float2(fmaf(a.x, b.x, -(a.y*b.y)), fmaf(a.x, b.y, a.y*b.x));
}
__device__ __forceinline__ float2 cmulc(float2 a, float2 b){ // a * conj(b)
  return make_float2(fmaf(a.x, b.x, a.y*b.y), fmaf(a.y, b.x, -(a.x*b.y)));
}

// Bank-decorrelating bijection on [0,512).
__device__ __forceinline__ int sg(int e){
  int d2 = (e>>6)&7, d1 = (e>>3)&7;
  return e ^ (d2<<3) ^ d1 ^ d2;
}

// ---- scoped global I/O (inline asm, manual waits) ----
__device__ __forceinline__ float2 u2f(unsigned long long u){ union{unsigned long long u; float2 f;}c; c.u=u; return c.f; }
__device__ __forceinline__ unsigned long long f2u(float2 f){ union{unsigned long long u; float2 f;}c; c.f=f; return c.u; }

__device__ __forceinline__ void gl_near(unsigned long long &d, unsigned long long bp, unsigned voff){
  asm volatile("global_load_dwordx2 %0, %1, %2 sc0" : "=&v"(d) : "v"(voff), "s"(bp) : "memory");
}
__device__ __forceinline__ void gl_far(unsigned long long &d, unsigned long long bp, unsigned voff){
  asm volatile("global_load_dwordx2 %0, %1, %2 sc0 sc1" : "=&v"(d) : "v"(voff), "s"(bp) : "memory");
}
__device__ __forceinline__ void gs_near(unsigned long long bp, unsigned voff, unsigned long long v){
  asm volatile("global_store_dwordx2 %0, %1, %2" :: "v"(voff), "v"(v), "s"(bp) : "memory");
}
__device__ __forceinline__ void gs_far(unsigned long long bp, unsigned voff, unsigned long long v){
  asm volatile("global_store_dwordx2 %0, %1, %2 sc0 sc1" :: "v"(voff), "v"(v), "s"(bp) : "memory");
}
__device__ __forceinline__ void vwait(){
  asm volatile("s_waitcnt vmcnt(0)" ::: "memory");
  __builtin_amdgcn_sched_barrier(0);
}

template<int INV>
__device__ __forceinline__ void dft8(float2 r[8]){
  const float RS = 0.7071067811865476f;
  float2 t0=cadd(r[0],r[4]), t4=csub(r[0],r[4]);
  float2 t1=cadd(r[1],r[5]), t5=csub(r[1],r[5]);
  float2 t2=cadd(r[2],r[6]), t6=csub(r[2],r[6]);
  float2 t3=cadd(r[3],r[7]), t7=csub(r[3],r[7]);
  float2 u1,u2,u3;
  if(!INV){
    u1 = make_float2((t5.x+t5.y)*RS, (t5.y-t5.x)*RS);
    u2 = make_float2(t6.y, -t6.x);
    u3 = make_float2((t7.y-t7.x)*RS, -(t7.x+t7.y)*RS);
  } else {
    u1 = make_float2((t5.x-t5.y)*RS, (t5.x+t5.y)*RS);
    u2 = make_float2(-t6.y, t6.x);
    u3 = make_float2(-(t7.x+t7.y)*RS, (t7.x-t7.y)*RS);
  }
  float2 e0=cadd(t0,t2), e1=csub(t0,t2), e2=cadd(t1,t3), e3=csub(t1,t3);
  float2 f3 = (!INV)? make_float2(e3.y,-e3.x) : make_float2(-e3.y,e3.x);
  r[0]=cadd(e0,e2); r[4]=csub(e0,e2); r[2]=cadd(e1,f3); r[6]=csub(e1,f3);
  float2 o0=cadd(t4,u2), o1=csub(t4,u2), o2=cadd(u1,u3), o3=csub(u1,u3);
  float2 g3 = (!INV)? make_float2(o3.y,-o3.x) : make_float2(-o3.y,o3.x);
  r[1]=cadd(o0,o2); r[5]=csub(o0,o2); r[3]=cadd(o1,g3); r[7]=csub(o1,g3);
}

// ---------- register-twiddle 512-pt FFTs (persistent kernel) ----------
__device__ __forceinline__ void fwd512(float2 r[8], int l, int p, int j,
                                       const float2* t1, const float2* t2, float2* ex){
  dft8<0>(r);
  #pragma unroll
  for(int q=1;q<8;q++) r[q]=cmul(r[q],t1[q-1]);
  #pragma unroll
  for(int q=0;q<8;q++) ex[sg(l+64*q)] = r[q];
  #pragma unroll
  for(int m=0;m<8;m++) r[m] = ex[sg(64*j+p+8*m)];
  dft8<0>(r);
  #pragma unroll
  for(int q=1;q<8;q++) r[q]=cmul(r[q],t2[q-1]);
  #pragma unroll
  for(int q=0;q<8;q++) ex[sg(64*j+p+8*q)] = r[q];
  #pragma unroll
  for(int m=0;m<8;m++) r[m] = ex[sg(64*j+8*p+m)];
  dft8<0>(r);
}
__device__ __forceinline__ void inv512(float2 r[8], int l, int p, int j,
                                       const float2* t1, const float2* t2, float2* ex){
  dft8<1>(r);
  #pragma unroll
  for(int m=0;m<8;m++) ex[sg(64*j+8*p+m)] = r[m];
  #pragma unroll
  for(int q=0;q<8;q++) r[q] = ex[sg(64*j+p+8*q)];
  #pragma unroll
  for(int q=1;q<8;q++) r[q]=cmulc(r[q],t2[q-1]);
  dft8<1>(r);
  #pragma unroll
  for(int m=0;m<8;m++) ex[sg(64*j+p+8*m)] = r[m];
  #pragma unroll
  for(int q=0;q<8;q++) r[q] = ex[sg(l+64*q)];
  #pragma unroll
  for(int q=1;q<8;q++) r[q]=cmulc(r[q],t1[q-1]);
  dft8<1>(r);
}

// ---------- original sincos-based fft512 (fallback kernels) ----------
template<int INV>
__device__ __forceinline__ void fft512(float2 r[8], int l, float2* ex){
  const float W512 = (float)(2.0*PI_D/512.0);
  const float W64  = (float)(2.0*PI_D/64.0);
  int j = l>>3, p = l&7;
  float s,c;
  if(!INV){
    dft8<0>(r);
    __sincosf(-W512*(float)l, &s, &c);
    float2 w = make_float2(c,s), cur = w;
    #pragma unroll
    for(int q=1;q<8;q++){ r[q]=cmul(r[q],cur); cur=cmul(cur,w); }
    #pragma unroll
    for(int q=0;q<8;q++) ex[sg(l + 64*q)] = r[q];
    #pragma unroll
    for(int m=0;m<8;m++) r[m] = ex[sg(64*j + p + 8*m)];
    dft8<0>(r);
    __sincosf(-W64*(float)p, &s, &c);
    w = make_float2(c,s); cur = w;
    #pragma unroll
    for(int q=1;q<8;q++){ r[q]=cmul(r[q],cur); cur=cmul(cur,w); }
    #pragma unroll
    for(int q=0;q<8;q++) ex[sg(64*j + p + 8*q)] = r[q];
    #pragma unroll
    for(int m=0;m<8;m++) r[m] = ex[sg(64*j + 8*p + m)];
    dft8<0>(r);
  } else {
    dft8<1>(r);
    #pragma unroll
    for(int m=0;m<8;m++) ex[sg(64*j + 8*p + m)] = r[m];
    #pragma unroll
    for(int q=0;q<8;q++) r[q] = ex[sg(64*j + p + 8*q)];
    __sincosf(W64*(float)p, &s, &c);
    float2 w = make_float2(c,s), cur = w;
    #pragma unroll
    for(int q=1;q<8;q++){ r[q]=cmul(r[q],cur); cur=cmul(cur,w); }
    dft8<1>(r);
    #pragma unroll
    for(int m=0;m<8;m++) ex[sg(64*j + p + 8*m)] = r[m];
    #pragma unroll
    for(int q=0;q<8;q++) r[q] = ex[sg(l + 64*q)];
    __sincosf(W512*(float)l, &s, &c);
    w = make_float2(c,s); cur = w;
    #pragma unroll
    for(int q=1;q<8;q++){ r[q]=cmul(r[q],cur); cur=cmul(cur,w); }
    dft8<1>(r);
  }
}

// Permuted dispersion tables + barrier/claim-slot zeroing.
__global__ __launch_bounds__(512) void kSetup(float2* __restrict__ dispF, float2* __restrict__ dispH,
                                              int* __restrict__ bar){
  int m  = blockIdx.x*512 + threadIdx.x;
  if (m < 16384) bar[m] = 0;
  int k1 = m >> 9, k2 = m & 511;
  int k  = k1 + (k2 << 9);
  int ks = (k < 131072) ? k : k - 262144;
  float fv  = (float)ks / 262144.0f;
  float tpf = 6.28318548202514648f * fv;
  float e2  = tpf * tpf;
  const float bh = 10.8350000381469727f;
  float phF = (bh * 1.25f)  * e2;
  float phH = (bh * 0.625f) * e2;
  double sF,cF,sH,cH;
  sincos((double)phF, &sF, &cF);
  sincos((double)phH, &sH, &cH);
  const float aco = -0.023000000044703484f;
  double scF = exp((double)(aco*1.25f))  / 262144.0;
  double scH = exp((double)(aco*0.625f)) / 262144.0;
  dispF[m] = make_float2((float)(cF*scF), (float)(sF*scF));
  dispH[m] = make_float2((float)(cH*scH), (float)(sH*scH));
}

// ---------------- fallback multi-kernel path (proven) ----------------
__global__ __launch_bounds__(512) void kA(const float2* __restrict__ src, float2* __restrict__ dst,
                                          const float2* __restrict__ disp){
  __shared__ float2 ex[8][512];
  int t = threadIdx.x, w = t>>6, l = t&63;
  int k1 = blockIdx.x*8 + w;
  size_t base = ((size_t)blockIdx.y<<18) + (size_t)k1*512;
  const float2* s = src + base;
  float2* d = dst + base;
  float2 r[8];
  #pragma unroll
  for(int m=0;m<8;m++) r[m] = s[l + 64*m];
  fft512<0>(r, l, ex[w]);
  int p=l&7, j=l>>3;
  const float2* dp = disp + (size_t)k1*512;
  #pragma unroll
  for(int q=0;q<8;q++) r[q] = cmul(r[q], dp[64*q + 8*p + j]);
  fft512<1>(r, l, ex[w]);
  float c1 = (float)(2.0*PI_D/262144.0)*(float)k1;
  float sb,cb,ss,cs;
  __sincosf(c1*(float)l, &sb, &cb);
  __sincosf(c1*64.0f,    &ss, &cs);
  float2 tw = make_float2(cb,sb), st = make_float2(cs,ss);
  #pragma unroll
  for(int m=0;m<8;m++){ d[l+64*m] = cmul(r[m], tw); tw = cmul(tw, st); }
}

template<int MODE>
__global__ __launch_bounds__(512) void kB(const float* __restrict__ xr, const float* __restrict__ xi,
                                          const float2* __restrict__ src, float2* __restrict__ dst,
                                          float* __restrict__ outp){
  __shared__ float2 tile[8][514];
  int t=threadIdx.x, w=t>>6, l=t&63;
  int c0 = blockIdx.x*8;
  size_t base = ((size_t)blockIdx.y<<18);
  #pragma unroll
  for(int i=0;i<8;i++){
    int rr = i*64 + (t>>3), cc = t&7;
    size_t a = base + (size_t)rr*512 + (size_t)(c0 + cc);
    if(MODE==0) tile[cc][sg(rr)] = make_float2(xr[a], xi[a]);
    else        tile[cc][sg(rr)] = src[a];
  }
  __syncthreads();
  float2 r[8];
  int p=l&7, j=l>>3;
  int n2 = c0 + w;
  if(MODE==0){
    #pragma unroll
    for(int m=0;m<8;m++) r[m] = tile[w][sg(l + 64*m)];
  } else {
    #pragma unroll
    for(int q=0;q<8;q++) r[q] = tile[w][sg(64*q + 8*p + j)];
    fft512<1>(r, l, tile[w]);
  }
  if(MODE==1){
    #pragma unroll
    for(int m=0;m<8;m++){
      int n1 = l + 64*m;
      float wv = 1.0f;
      if(n1==0 && n2<100){
        float ang = (6.28318548202514648f*(float)n2)*0.005f;
        wv = 0.54f - 0.46f*cosf(ang);
      } else if(n1==511 && n2>=412){
        float ang = (6.28318548202514648f*(float)(n2-312))*0.005f;
        wv = 0.54f - 0.46f*cosf(ang);
      }
      float2 qv = make_float2(r[m].x*wv, r[m].y*wv);
      float aq2 = fmaf(qv.x,qv.x, qv.y*qv.y);
      float phi = (aq2 * 1.26999998092651367f) * (-1.25f);
      float sp,cp; __sincosf(phi,&sp,&cp);
      r[m] = cmul(qv, make_float2(cp,sp));
    }
  }
  if(MODE==2){
    #pragma unroll
    for(int m=0;m<8;m++) tile[w][sg(l + 64*m)] = r[m];
    __syncthreads();
    #pragma unroll
    for(int i=0;i<8;i++){
      int rr = i*64 + (t>>3), cc = t&7;
      float2 v = tile[cc][sg(rr)];
      size_t a = base + (size_t)rr*512 + (size_t)(c0 + cc);
      outp[a] = v.x;
      outp[(size_t)(1<<20) + a] = v.y;
    }
    return;
  }
  fft512<0>(r, l, tile[w]);
  float c1 = -(float)(2.0*PI_D/262144.0)*(float)n2;
  float sb,cb,ss,cs;
  __sincosf(c1*(float)(8*p + j), &sb, &cb);
  __sincosf(c1*64.0f,            &ss, &cs);
  float2 tw=make_float2(cb,sb), st=make_float2(cs,ss);
  #pragma unroll
  for(int q=0;q<8;q++){ r[q]=cmul(r[q],tw); tw=cmul(tw,st); }
  #pragma unroll
  for(int q=0;q<8;q++) tile[w][sg(64*q + 8*p + j)] = r[q];
  __syncthreads();
  #pragma unroll
  for(int i=0;i<8;i++){
    int rr = i*64 + (t>>3), cc = t&7;
    dst[base + (size_t)rr*512 + (size_t)(c0 + cc)] = tile[cc][sg(rr)];
  }
}

// ---------------- persistent cooperative kernel ----------------
// One-shot barrier per (batch, phase). Entry drains asm stores (vmcnt).
__device__ __forceinline__ void gsync(int* bar, int slotbase, int phase){
  asm volatile("s_waitcnt vmcnt(0)" ::: "memory");
  __syncthreads();
  if (threadIdx.x == 0){
    int* cnt = bar + slotbase + phase*16;
    __hip_atomic_fetch_add(cnt, 1, __ATOMIC_RELAXED, __HIP_MEMORY_SCOPE_AGENT);
    while (__hip_atomic_load(cnt, __ATOMIC_RELAXED, __HIP_MEMORY_SCOPE_AGENT) != 64)
      __builtin_amdgcn_s_sleep(1);
    asm volatile("" ::: "memory");
  }
  __syncthreads();
}
__device__ __forceinline__ void gsyncAll(int* bar){
  asm volatile("s_waitcnt vmcnt(0)" ::: "memory");
  __syncthreads();
  if (threadIdx.x == 0){
    int* cnt = bar + 9000;
    __hip_atomic_fetch_add(cnt, 1, __ATOMIC_RELAXED, __HIP_MEMORY_SCOPE_AGENT);
    while (__hip_atomic_load(cnt, __ATOMIC_RELAXED, __HIP_MEMORY_SCOPE_AGENT) != 256)
      __builtin_amdgcn_s_sleep(1);
    asm volatile("" ::: "memory");
  }
  __syncthreads();
}

__global__ __launch_bounds__(512, 1) void ssfm_all(
    const float* __restrict__ xr, const float* __restrict__ xi,
    float* __restrict__ outp,
    float2* __restrict__ buf1, float2* __restrict__ buf2,
    const float2* __restrict__ dispF, const float2* __restrict__ dispH,
    int* __restrict__ bar, int* __restrict__ xcdtab)
{
  __shared__ float2 tile[8][514];
  __shared__ int sxcd[64];
  __shared__ int s_lb;
  const int t=threadIdx.x, w=t>>6, l=t&63, p=l&7, j=l>>3;

  // ---- physical-XCD-aware slot claim: batch = XCD pair by construction ----
  int myx;
  asm("s_getreg_b32 %0, hwreg(HW_REG_XCC_ID)" : "=s"(myx));
  myx &= 7;
  if (t==0){
    int r = atomicAdd(&bar[10304+myx], 1);       // rank within my XCD
    int lbv = -1;
    if (r < 32){
      int pref = myx*32 + r;
      if (atomicCAS(&bar[10000+pref],0,1)==0) lbv = pref;
    }
    if (lbv < 0){                                 // non-uniform dispatch fallback
      for (int s=0; s<256 && lbv<0; ++s)
        if (atomicCAS(&bar[10000+s],0,1)==0) lbv = s;
    }
    s_lb = lbv;
  }
  __syncthreads();
  const int lb = s_lb;
  const int b=lb>>6, g=lb&63;
  const size_t base=(size_t)b<<18;
  const int k1=g*8+w, c0=g*8, n2=c0+w;
  const int slotbase = b*140*16;
  float2* exch = tile[w];
  const unsigned long long b1p=(unsigned long long)buf1, b2p=(unsigned long long)buf2;

  // publish XCD table, derive wave-uniform near mask (bit i: peer unit 8i+w)
  if (t==0)
    __hip_atomic_store(&xcdtab[lb], myx, __ATOMIC_RELAXED, __HIP_MEMORY_SCOPE_AGENT);
  gsyncAll(bar);
  if (t<64)
    sxcd[t] = __hip_atomic_load(&xcdtab[b*64+t], __ATOMIC_RELAXED, __HIP_MEMORY_SCOPE_AGENT);
  __syncthreads();
  int smask=0;
  #pragma unroll
  for(int i=0;i<8;i++) smask |= (sxcd[8*i+w]==myx) ? (1<<i) : 0;
  smask = __builtin_amdgcn_readfirstlane(smask);

  // one-time register cache
  float2 t1[7], t2[7], dpF[8], dpH[8];
  #pragma unroll
  for(int q=1;q<8;q++){
    double s,c;
    sincos(-2.0*PI_D*(double)(l*q)/512.0,&s,&c); t1[q-1]=make_float2((float)c,(float)s);
    sincos(-2.0*PI_D*(double)(p*q)/64.0,&s,&c);  t2[q-1]=make_float2((float)c,(float)s);
  }
  float2 baseA, stA, baseB, stB;
  {
    double s,c;
    sincos( 2.0*PI_D*(double)(k1*l)/262144.0,&s,&c);        baseA=make_float2((float)c,(float)s);
    sincos( 2.0*PI_D*(double)(k1*64)/262144.0,&s,&c);       stA  =make_float2((float)c,(float)s);
    sincos(-2.0*PI_D*(double)(n2*(8*p+j))/262144.0,&s,&c);  baseB=make_float2((float)c,(float)s);
    sincos(-2.0*PI_D*(double)(n2*64)/262144.0,&s,&c);       stB  =make_float2((float)c,(float)s);
  }
  #pragma unroll
  for(int q=0;q<8;q++){
    int di=k1*512+64*q+8*p+j;
    dpF[q]=dispF[di]; dpH[q]=dispH[di];
  }
  float wvH=1.0f, wvT=1.0f;
  if(l==0  && n2<100)  wvH=0.54f-0.46f*cosf((6.28318548202514648f*(float)n2)*0.005f);
  if(l==63 && n2>=412) wvT=0.54f-0.46f*cosf((6.28318548202514648f*(float)(n2-312))*0.005f);

  // staging thread coords
  const int cc8 = t&7, q8 = t>>3;
  // tile-blocked addressing: tile T=R*64+C occupies f2 [T*64, T*64+64).
  // B-phase wave w, iter i <-> tile (R=8i+w, C=g), lane l <-> element l.
  const unsigned voffB0 = (unsigned)((base + (size_t)w*4096 + (size_t)g*64 + (size_t)l)*8);
  // A-phase wave w, iter i <-> tile (R=g, C=8i+w), lane l <-> element ((t&7)<<3)|((t>>3)&7).
  const unsigned voffA0 = (unsigned)((base + (size_t)g*4096 + (size_t)w*64
                                      + (size_t)(((t&7)<<3)|((t>>3)&7)))*8);

  // ---- B0: input (row-major) -> forward col-FFT -> twiddle -> buf1 (tiles) ----
  {
    #pragma unroll
    for(int i=0;i<8;i++){
      int rr=i*64+q8;
      size_t a=base+(size_t)rr*512+(size_t)(c0+cc8);
      tile[cc8][sg(rr)]=make_float2(xr[a], xi[a]);
    }
    __syncthreads();
    float2 r[8];
    #pragma unroll
    for(int m=0;m<8;m++) r[m]=exch[sg(l+64*m)];
    fwd512(r,l,p,j,t1,t2,exch);
    float2 tw=baseB;
    #pragma unroll
    for(int q=0;q<8;q++){ r[q]=cmul(r[q],tw); tw=cmul(tw,stB); }
    #pragma unroll
    for(int q=0;q<8;q++) exch[sg(64*q+8*p+j)]=r[q];
    __syncthreads();
    unsigned voff=voffB0;
    #pragma unroll
    for(int i=0;i<8;i++){
      unsigned long long v=f2u(tile[cc8][sg(i*64+q8)]);
      if(smask&(1<<i)) gs_near(b1p,voff,v); else gs_far(b1p,voff,v);
      voff += 262144u;
    }
  }
  gsync(bar, slotbase, 0);
  // ---- A(half-dz): buf1 -> buf2 (LDS-staged rows, tile addressing) ----
  {
    unsigned long long v[8]; unsigned voff=voffA0;
    #pragma unroll
    for(int i=0;i<8;i++){
      if(smask&(1<<i)) gl_near(v[i],b1p,voff); else gl_far(v[i],b1p,voff);
      voff += 4096u;
    }
    vwait();
    #pragma unroll
    for(int i=0;i<8;i++) tile[cc8][sg(i*64+q8)] = u2f(v[i]);
    __syncthreads();
    float2 r[8];
    #pragma unroll
    for(int m=0;m<8;m++) r[m]=exch[sg(l+64*m)];
    fwd512(r,l,p,j,t1,t2,exch);
    #pragma unroll
    for(int q=0;q<8;q++) r[q]=cmul(r[q],dpH[q]);
    inv512(r,l,p,j,t1,t2,exch);
    float2 tw=baseA;
    #pragma unroll
    for(int m=0;m<8;m++){ exch[sg(l+64*m)]=cmul(r[m],tw); tw=cmul(tw,stA); }
    __syncthreads();
    voff=voffA0;
    #pragma unroll
    for(int i=0;i<8;i++){
      unsigned long long vv=f2u(tile[cc8][sg(i*64+q8)]);
      if(smask&(1<<i)) gs_near(b2p,voff,vv); else gs_far(b2p,voff,vv);
      voff += 4096u;
    }
  }
  gsync(bar, slotbase, 1);

  #pragma unroll 1
  for(int it=0; it<64; ++it){
    // ---- B1: buf2 -> inv col-FFT -> window -> NL -> fwd col-FFT -> buf1 ----
    {
      unsigned long long v[8]; unsigned voff=voffB0;
      #pragma unroll
      for(int i=0;i<8;i++){
        if(smask&(1<<i)) gl_near(v[i],b2p,voff); else gl_far(v[i],b2p,voff);
        voff += 262144u;
      }
      vwait();
      #pragma unroll
      for(int i=0;i<8;i++) tile[cc8][sg(i*64+q8)] = u2f(v[i]);
      __syncthreads();
      float2 r[8];
      #pragma unroll
      for(int q=0;q<8;q++) r[q]=exch[sg(64*q+8*p+j)];
      inv512(r,l,p,j,t1,t2,exch);
      #pragma unroll
      for(int m=0;m<8;m++){
        float wv = (m==0)? wvH : ((m==7)? wvT : 1.0f);
        float2 qv=make_float2(r[m].x*wv, r[m].y*wv);
        float aq2=fmaf(qv.x,qv.x, qv.y*qv.y);
        float phi=(aq2*1.26999998092651367f)*(-1.25f);
        float sp,cp; __sincosf(phi,&sp,&cp);
        r[m]=cmul(qv,make_float2(cp,sp));
      }
      fwd512(r,l,p,j,t1,t2,exch);
      float2 tw=baseB;
      #pragma unroll
      for(int q=0;q<8;q++){ r[q]=cmul(r[q],tw); tw=cmul(tw,stB); }
      #pragma unroll
      for(int q=0;q<8;q++) exch[sg(64*q+8*p+j)]=r[q];
      __syncthreads();
      voff=voffB0;
      #pragma unroll
      for(int i=0;i<8;i++){
        unsigned long long vv=f2u(tile[cc8][sg(i*64+q8)]);
        if(smask&(1<<i)) gs_near(b1p,voff,vv); else gs_far(b1p,voff,vv);
        voff += 262144u;
      }
    }
    gsync(bar, slotbase, 2+2*it);
    // ---- A: buf1 -> buf2 (dz; last iteration dz/2) ----
    {
      unsigned long long v[8]; unsigned voff=voffA0;
      #pragma unroll
      for(int i=0;i<8;i++){
        if(smask&(1<<i)) gl_near(v[i],b1p,voff); else gl_far(v[i],b1p,voff);
        voff += 4096u;
      }
      vwait();
      #pragma unroll
      for(int i=0;i<8;i++) tile[cc8][sg(i*64+q8)] = u2f(v[i]);
      __syncthreads();
      float2 r[8];
      #pragma unroll
      for(int m=0;m<8;m++) r[m]=exch[sg(l+64*m)];
      fwd512(r,l,p,j,t1,t2,exch);
      const bool lastH=(it==63);
      #pragma unroll
      for(int q=0;q<8;q++){ float2 dq = lastH? dpH[q] : dpF[q]; r[q]=cmul(r[q],dq); }
      inv512(r,l,p,j,t1,t2,exch);
      float2 tw=baseA;
      #pragma unroll
      for(int m=0;m<8;m++){ exch[sg(l+64*m)]=cmul(r[m],tw); tw=cmul(tw,stA); }
      __syncthreads();
      voff=voffA0;
      #pragma unroll
      for(int i=0;i<8;i++){
        unsigned long long vv=f2u(tile[cc8][sg(i*64+q8)]);
        if(smask&(1<<i)) gs_near(b2p,voff,vv); else gs_far(b2p,voff,vv);
        voff += 4096u;
      }
    }
    gsync(bar, slotbase, 3+2*it);
  }

  // ---- B2: buf2 (tiles) -> inv col-FFT -> output planes (row-major) ----
  {
    unsigned long long v[8]; unsigned voff=voffB0;
    #pragma unroll
    for(int i=0;i<8;i++){
      if(smask&(1<<i)) gl_near(v[i],b2p,voff); else gl_far(v[i],b2p,voff);
      voff += 262144u;
    }
    vwait();
    #pragma unroll
    for(int i=0;i<8;i++) tile[cc8][sg(i*64+q8)] = u2f(v[i]);
    __syncthreads();
    float2 r[8];
    #pragma unroll
    for(int q=0;q<8;q++) r[q]=exch[sg(64*q+8*p+j)];
    inv512(r,l,p,j,t1,t2,exch);
    #pragma unroll
    for(int m=0;m<8;m++) exch[sg(l+64*m)]=r[m];
    __syncthreads();
    #pragma unroll
    for(int i=0;i<8;i++){
      int rr=i*64+q8;
      float2 vv=tile[cc8][sg(rr)];
      size_t a=base+(size_t)rr*512+(size_t)(c0+cc8);
      outp[a]=vv.x;
      outp[(size_t)(1<<20)+a]=vv.y;
    }
  }
}

extern "C" void kernel_launch(void* const* d_in, const int* in_sizes, int n_in,
                              void* d_out, int out_size, void* d_ws, size_t ws_size,
                              hipStream_t stream) {
  (void)in_sizes; (void)n_in; (void)out_size; (void)ws_size;
  const float* xr = (const float*)d_in[0];
  const float* xi = (const float*)d_in[1];
  float* out = (float*)d_out;
  char* ws = (char*)d_ws;
  float2* buf1  = (float2*)ws;                      // 8 MB
  float2* buf2  = (float2*)(ws + ((size_t)8<<20));  // 8 MB
  float2* dispF = (float2*)(ws + ((size_t)16<<20)); // 2 MB
  float2* dispH = (float2*)(ws + ((size_t)18<<20)); // 2 MB
  int*    bar   = (int*)   (ws + ((size_t)20<<20)); // 64 KB barrier/claim slots
  int*    xcdt  = (int*)   (ws + ((size_t)21<<20)); // 1 KB XCD table

  kSetup<<<dim3(512), dim3(512), 0, stream>>>(dispF, dispH, bar);

  void* args[] = {(void*)&xr,(void*)&xi,(void*)&out,(void*)&buf1,(void*)&buf2,
                  (void*)&dispF,(void*)&dispH,(void*)&bar,(void*)&xcdt};
  hipError_t e = hipLaunchCooperativeKernel((void*)ssfm_all, dim3(256), dim3(512),
                                            args, 0, stream);
  if (e != hipSuccess){
    // fallback: proven multi-kernel chain
    dim3 blk(512), gdim(64,4);
    kB<0><<<gdim, blk, 0, stream>>>(xr, xi, nullptr, buf1, nullptr);
    kA<<<gdim, blk, 0, stream>>>(buf1, buf2, dispH);
    for(int i=0;i<63;i++){
      kB<1><<<gdim, blk, 0, stream>>>(nullptr, nullptr, buf2, buf1, nullptr);
      kA<<<gdim, blk, 0, stream>>>(buf1, buf2, dispF);
    }
    kB<1><<<gdim, blk, 0, stream>>>(nullptr, nullptr, buf2, buf1, nullptr);
    kA<<<gdim, blk, 0, stream>>>(buf1, buf2, dispH);
    kB<2><<<gdim, blk, 0, stream>>>(nullptr, nullptr, buf2, nullptr, out);
  }
}